// Round 13
// baseline (303.189 us; speedup 1.0000x reference)
//
#include <hip/hip_runtime.h>
#include <hip/hip_cooperative_groups.h>
#include <cmath>

namespace cg = cooperative_groups;

#define N_NODES 50000
#define N_EDGES 800000
#define NBUCK 196          // buckets of 256 nodes: bucket = dst >> 8
#define NHB 196            // histogram blocks, 4096 edges each
#define EPB 4096
// IN_DIM = HEADS*HID = 128, HEADS=4, HID=32

typedef unsigned short u16;
typedef unsigned int u32;
typedef __attribute__((ext_vector_type(8))) short bf16x8;
typedef __attribute__((ext_vector_type(4))) float f32x4;

static __device__ __forceinline__ float lrelu(float x) { return x > 0.f ? x : 0.2f * x; }
static __device__ __forceinline__ float bf2f(u16 u) { return __uint_as_float(((u32)u) << 16); }
static __device__ __forceinline__ u16 f2bf(float f) {
    u32 b = __float_as_uint(f);
    return (u16)((b + 0x7FFFu + ((b >> 16) & 1u)) >> 16);  // RNE
}
static __device__ __forceinline__ u32 pack2(float a, float b) {
    return (u32)f2bf(a) | ((u32)f2bf(b) << 16);
}
// sign-extended byte k of u -> float
static __device__ __forceinline__ float sx(u32 u, int k) {
    return (float)((int)(u << ((3 - k) * 8)) >> 24);
}

// ================= fused cooperative CSR build (+ weight pre-pack) =================
// 196 blocks x 1024 threads, grid.sync() between phases (all blocks co-resident:
// 196x16=3136 waves << 8192 device capacity).
// P1: per-block bucket histogram (transposed store) + packW (blocks 0..31)
// P2: per-bucket exclusive scan over hist blocks -> wbase, btot
// P2b: every block redundantly scans btot -> bucket starts in LDS
// P3: scatter edges into bucket-contiguous 'bucketed'
// P4: per-bucket fine CSR: node offs + u16 srcs
__global__ __launch_bounds__(1024) void csr_coop_k(
    const int* __restrict__ src, const int* __restrict__ dst,
    const float* __restrict__ W1, const float* __restrict__ W2,
    u16* __restrict__ Wp1, u16* __restrict__ Wp2,
    u32* __restrict__ bcnt, u32* __restrict__ wbase, u32* __restrict__ btot,
    u32* __restrict__ bucketed, int* __restrict__ offs, u16* __restrict__ srcs)
{
    cg::grid_group grid = cg::this_grid();
    __shared__ u32 hist[NBUCK];          // P1 histogram, P3 write-cursors
    __shared__ u32 s[256];               // scan scratch
    __shared__ int bstart_s[NBUCK + 1];  // bucket starts (P2b), used P3/P4
    __shared__ u32 cnt[256];             // P4 per-node counts
    __shared__ u32 fp[256];              // P4 fill cursors
    int tid = threadIdx.x;
    int blk = blockIdx.x;
    int base = blk * EPB;

    // ---- P1: histogram + packW ----
    for (int i = tid; i < NBUCK; i += 1024) hist[i] = 0;
    __syncthreads();
#pragma unroll
    for (int k = 0; k < 4; ++k) {
        int e = base + k * 1024 + tid;
        if (e < N_EDGES) atomicAdd(&hist[dst[e] >> 8], 1u);
    }
    {
        int gi = blk * 1024 + tid;
        if (gi < 32768) {
            const float* W = (gi < 16384) ? W1 : W2;
            u16* Wp = (gi < 16384) ? Wp1 : Wp2;
            int i = gi & 16383;
            int j = i & 7, lane = (i >> 3) & 63, ks = (i >> 9) & 3, nt = i >> 11;
            int k = ks * 32 + (lane >> 4) * 8 + j;
            int ncol = nt * 16 + (lane & 15);
            Wp[i] = f2bf(W[k * 128 + ncol]);
        }
    }
    __syncthreads();
    for (int i = tid; i < NBUCK; i += 1024) bcnt[(size_t)i * NHB + blk] = hist[i];
    grid.sync();

    // ---- P2: scan bucket 'blk' over its 196 hist blocks ----
    {
        u32 v = 0;
        if (tid < 256) {
            v = (tid < NHB) ? bcnt[(size_t)blk * NHB + tid] : 0;
            s[tid] = v;
        }
        __syncthreads();
        for (int o = 1; o < 256; o <<= 1) {
            u32 x = 0;
            if (tid < 256 && tid >= o) x = s[tid - o];
            __syncthreads();
            if (tid < 256) s[tid] += x;
            __syncthreads();
        }
        if (tid < NHB) wbase[(size_t)blk * NHB + tid] = s[tid] - v;
        if (tid == 255) btot[blk] = s[255];
    }
    grid.sync();

    // ---- P2b: redundant bucket-start scan into LDS ----
    {
        u32 v = 0;
        if (tid < 256) {
            v = (tid < NBUCK) ? btot[tid] : 0;
            s[tid] = v;
        }
        __syncthreads();
        for (int o = 1; o < 256; o <<= 1) {
            u32 x = 0;
            if (tid < 256 && tid >= o) x = s[tid - o];
            __syncthreads();
            if (tid < 256) s[tid] += x;
            __syncthreads();
        }
        if (tid < NBUCK) bstart_s[tid] = (int)(s[tid] - v);
        if (tid == NBUCK - 1) bstart_s[NBUCK] = (int)s[tid];
        __syncthreads();
    }

    // ---- P3: scatter this block's edges ----
    for (int i = tid; i < NBUCK; i += 1024)
        hist[i] = (u32)bstart_s[i] + wbase[(size_t)i * NHB + blk];
    __syncthreads();
#pragma unroll
    for (int k = 0; k < 4; ++k) {
        int e = base + k * 1024 + tid;
        if (e < N_EDGES) {
            int d = dst[e];
            int b = d >> 8;
            u32 p = atomicAdd(&hist[b], 1u);
            bucketed[p] = (u32)src[e] | ((u32)(d & 255) << 16);
        }
    }
    grid.sync();

    // ---- P4: fine CSR for bucket 'blk' ----
    int ebeg = bstart_s[blk], eend = bstart_s[blk + 1];
    int ne = eend - ebeg;
    if (tid < 256) cnt[tid] = 0;
    __syncthreads();
    for (int i = tid; i < ne; i += 1024)
        atomicAdd(&cnt[bucketed[ebeg + i] >> 16], 1u);
    __syncthreads();
    u32 cv = 0;
    if (tid < 256) { cv = cnt[tid]; s[tid] = cv; }
    __syncthreads();
    for (int o = 1; o < 256; o <<= 1) {
        u32 x = 0;
        if (tid < 256 && tid >= o) x = s[tid - o];
        __syncthreads();
        if (tid < 256) s[tid] += x;
        __syncthreads();
    }
    if (tid < 256) {
        int excl = (int)(s[tid] - cv);
        int node = blk * 256 + tid;
        if (node < N_NODES) offs[node] = ebeg + excl;
        fp[tid] = (u32)excl;
    }
    if (blk == NBUCK - 1 && tid == 0) offs[N_NODES] = N_EDGES;
    __syncthreads();
    for (int i = tid; i < ne; i += 1024) {
        u32 u = bucketed[ebeg + i];
        u32 p = atomicAdd(&fp[u >> 16], 1u);
        srcs[ebeg + p] = (u16)(u & 0xFFFFu);
    }
}

// ---------------- MFMA GEMM -> int8 hf + fused {el,scale} float2 + er ----------------
// hq: int8 [N][128]; elhs: float2 [N][4] = {el, absmax/127}; er: fp32 [N][4]. wave = head.
template <int BF16IN>
__global__ __launch_bounds__(256) void gemm_mfma(
    const void* __restrict__ Xv, const u16* __restrict__ Wp,
    const float* __restrict__ al, const float* __restrict__ ar,
    signed char* __restrict__ hq, float2* __restrict__ elhs, float* __restrict__ er, int n)
{
    __shared__ u16 xs[64][136];   // +8 pad: 2-way LDS bank aliasing (free)
    int row0 = blockIdx.x * 64;
    int tid = threadIdx.x;
    if (BF16IN) {
        const uint4* Xb = (const uint4*)Xv;
        for (int i = tid; i < 1024; i += 256) {
            int r = i >> 4, c = i & 15;
            uint4 v = make_uint4(0u, 0u, 0u, 0u);
            if (row0 + r < n) v = Xb[(size_t)(row0 + r) * 16 + c];
            ((uint4*)&xs[r][0])[c] = v;
        }
    } else {
        const float4* X4 = (const float4*)Xv;
        for (int i = tid; i < 2048; i += 256) {
            int r = i >> 5, c = i & 31;
            float4 v = make_float4(0.f, 0.f, 0.f, 0.f);
            if (row0 + r < n) v = X4[(size_t)(row0 + r) * 32 + c];
            ((uint2*)&xs[r][0])[c] = make_uint2(pack2(v.x, v.y), pack2(v.z, v.w));
        }
    }
    __syncthreads();

    int wave = tid >> 6, lane = tid & 63;
    int quad = lane >> 4, l15 = lane & 15;

    bf16x8 bfrag[2][4];
#pragma unroll
    for (int ct = 0; ct < 2; ++ct) {
        int nt = wave * 2 + ct;
#pragma unroll
        for (int ks = 0; ks < 4; ++ks)
            bfrag[ct][ks] = *(const bf16x8*)(Wp + ((((nt * 4 + ks) * 64) + lane) << 3));
    }

    f32x4 acc[4][2];
#pragma unroll
    for (int rt = 0; rt < 4; ++rt)
#pragma unroll
        for (int ct = 0; ct < 2; ++ct)
            acc[rt][ct] = (f32x4){0.f, 0.f, 0.f, 0.f};

#pragma unroll
    for (int ks = 0; ks < 4; ++ks) {
#pragma unroll
        for (int rt = 0; rt < 4; ++rt) {
            bf16x8 a = *(const bf16x8*)&xs[rt * 16 + l15][ks * 32 + quad * 8];
            acc[rt][0] = __builtin_amdgcn_mfma_f32_16x16x32_bf16(a, bfrag[0][ks], acc[rt][0], 0, 0, 0);
            acc[rt][1] = __builtin_amdgcn_mfma_f32_16x16x32_bf16(a, bfrag[1][ks], acc[rt][1], 0, 0, 0);
        }
    }

    float alv0 = al[wave * 32 + l15], alv1 = al[wave * 32 + 16 + l15];
    float arv0 = ar[wave * 32 + l15], arv1 = ar[wave * 32 + 16 + l15];
#pragma unroll
    for (int rt = 0; rt < 4; ++rt) {
#pragma unroll
        for (int r = 0; r < 4; ++r) {
            int row = row0 + rt * 16 + quad * 4 + r;
            float c0 = acc[rt][0][r], c1 = acc[rt][1][r];
            // per-(row, head) absmax over the wave's 32 cols (reduce over l15 lanes)
            float m = fmaxf(fabsf(c0), fabsf(c1));
            m = fmaxf(m, __shfl_xor(m, 1));
            m = fmaxf(m, __shfl_xor(m, 2));
            m = fmaxf(m, __shfl_xor(m, 4));
            m = fmaxf(m, __shfl_xor(m, 8));
            m = fmaxf(m, 1e-20f);
            float qsc = 127.0f / m;
            if (row < n) {
                hq[(size_t)row * 128 + wave * 32 + l15] = (signed char)(int)rintf(c0 * qsc);
                hq[(size_t)row * 128 + wave * 32 + 16 + l15] = (signed char)(int)rintf(c1 * qsc);
            }
            float pel = c0 * alv0 + c1 * alv1;
            float per = c0 * arv0 + c1 * arv1;
            pel += __shfl_xor(pel, 1); pel += __shfl_xor(pel, 2);
            pel += __shfl_xor(pel, 4); pel += __shfl_xor(pel, 8);
            per += __shfl_xor(per, 1); per += __shfl_xor(per, 2);
            per += __shfl_xor(per, 4); per += __shfl_xor(per, 8);
            if (l15 == 0 && row < n) {
                elhs[row * 4 + wave] = make_float2(pel, m * (1.0f / 127.0f));
                er[row * 4 + wave] = per;
            }
        }
    }
}

// ---------------- agg core: quarter-wave per edge, lane owns 8 int8 features (uint2) ---------
static __device__ __forceinline__ void agg_core(
    int node, int lane, const int* __restrict__ offs, const u16* __restrict__ srcs,
    const float2* __restrict__ elhs, const float* __restrict__ er,
    const signed char* __restrict__ hq,
    float acc[8], float& den)
{
    int qw = lane >> 4;
    int q = lane & 15;
    int h = q >> 2;
    float erh = er[node * 4 + h];
    int beg = offs[node], end = offs[node + 1];
    int deg = end - beg;
    den = 0.f;
#pragma unroll
    for (int i = 0; i < 8; i++) acc[i] = 0.f;

    if (deg <= 64) {
        int psrc = (lane < deg) ? (int)srcs[beg + lane] : 0;
        int base = beg;
        for (; base + 16 <= end; base += 16) {
            int j = base - beg + qw;
            int ss[4];
            ss[0] = __shfl(psrc, j);
            ss[1] = __shfl(psrc, j + 4);
            ss[2] = __shfl(psrc, j + 8);
            ss[3] = __shfl(psrc, j + 12);
            float2 eh[4];
            uint2 uv[4];
#pragma unroll
            for (int k = 0; k < 4; ++k) {
                eh[k] = elhs[ss[k] * 4 + h];
                uv[k] = *(const uint2*)(hq + (size_t)ss[k] * 128 + q * 8);
            }
#pragma unroll
            for (int k = 0; k < 4; ++k) {
                float w = __expf(lrelu(eh[k].x + erh));
                float ws = w * eh[k].y;
                den += w;
                acc[0] += ws * sx(uv[k].x, 0);
                acc[1] += ws * sx(uv[k].x, 1);
                acc[2] += ws * sx(uv[k].x, 2);
                acc[3] += ws * sx(uv[k].x, 3);
                acc[4] += ws * sx(uv[k].y, 0);
                acc[5] += ws * sx(uv[k].y, 1);
                acc[6] += ws * sx(uv[k].y, 2);
                acc[7] += ws * sx(uv[k].y, 3);
            }
        }
        for (; base + 8 <= end; base += 8) {
            int j = base - beg + qw;
            int s0 = __shfl(psrc, j);
            int s1 = __shfl(psrc, j + 4);
            float2 e0 = elhs[s0 * 4 + h], e1 = elhs[s1 * 4 + h];
            uint2 u0 = *(const uint2*)(hq + (size_t)s0 * 128 + q * 8);
            uint2 u1 = *(const uint2*)(hq + (size_t)s1 * 128 + q * 8);
            float w0 = __expf(lrelu(e0.x + erh));
            float w1 = __expf(lrelu(e1.x + erh));
            float ws0 = w0 * e0.y, ws1 = w1 * e1.y;
            den += w0 + w1;
            acc[0] += ws0 * sx(u0.x, 0) + ws1 * sx(u1.x, 0);
            acc[1] += ws0 * sx(u0.x, 1) + ws1 * sx(u1.x, 1);
            acc[2] += ws0 * sx(u0.x, 2) + ws1 * sx(u1.x, 2);
            acc[3] += ws0 * sx(u0.x, 3) + ws1 * sx(u1.x, 3);
            acc[4] += ws0 * sx(u0.y, 0) + ws1 * sx(u1.y, 0);
            acc[5] += ws0 * sx(u0.y, 1) + ws1 * sx(u1.y, 1);
            acc[6] += ws0 * sx(u0.y, 2) + ws1 * sx(u1.y, 2);
            acc[7] += ws0 * sx(u0.y, 3) + ws1 * sx(u1.y, 3);
        }
        for (; base < end; base += 4) {
            int e = base + qw;
            bool valid = e < end;
            int j = valid ? (e - beg) : 0;
            int s = __shfl(psrc, j);
            float2 eh = elhs[s * 4 + h];
            float w = valid ? __expf(lrelu(eh.x + erh)) : 0.f;
            float ws = w * eh.y;
            uint2 u = *(const uint2*)(hq + (size_t)s * 128 + q * 8);
            den += w;
            acc[0] += ws * sx(u.x, 0);
            acc[1] += ws * sx(u.x, 1);
            acc[2] += ws * sx(u.x, 2);
            acc[3] += ws * sx(u.x, 3);
            acc[4] += ws * sx(u.y, 0);
            acc[5] += ws * sx(u.y, 1);
            acc[6] += ws * sx(u.y, 2);
            acc[7] += ws * sx(u.y, 3);
        }
    } else {
        for (int base = beg; base < end; base += 4) {
            int e = base + qw;
            bool valid = e < end;
            int ec = valid ? e : end - 1;
            int s = srcs[ec];
            float2 eh = elhs[s * 4 + h];
            float w = valid ? __expf(lrelu(eh.x + erh)) : 0.f;
            float ws = w * eh.y;
            uint2 u = *(const uint2*)(hq + (size_t)s * 128 + q * 8);
            den += w;
            acc[0] += ws * sx(u.x, 0);
            acc[1] += ws * sx(u.x, 1);
            acc[2] += ws * sx(u.x, 2);
            acc[3] += ws * sx(u.x, 3);
            acc[4] += ws * sx(u.y, 0);
            acc[5] += ws * sx(u.y, 1);
            acc[6] += ws * sx(u.y, 2);
            acc[7] += ws * sx(u.y, 3);
        }
    }
#pragma unroll
    for (int i = 0; i < 8; i++) {
        acc[i] += __shfl_xor(acc[i], 16);
        acc[i] += __shfl_xor(acc[i], 32);
    }
    den += __shfl_xor(den, 16);
    den += __shfl_xor(den, 32);
}

// ---------------- layer-1 aggregation (relu, bf16 out node-major) ----------------
__global__ __launch_bounds__(256) void agg1_k(const int* __restrict__ offs, const u16* __restrict__ srcs,
                                              const float2* __restrict__ elhs, const float* __restrict__ er,
                                              const signed char* __restrict__ hq,
                                              const float* __restrict__ bias, u16* __restrict__ h1) {
    int node = blockIdx.x * 4 + (threadIdx.x >> 6);
    int lane = threadIdx.x & 63;
    if (node >= N_NODES) return;
    float acc[8], den;
    agg_core(node, lane, offs, srcs, elhs, er, hq, acc, den);
    int qw = lane >> 4, q = lane & 15;
    if (qw == 0) {
        float inv = 1.0f / fmaxf(den, 1e-30f);
        float o[8];
#pragma unroll
        for (int i = 0; i < 8; i++)
            o[i] = fmaxf(acc[i] * inv + bias[q * 8 + i], 0.f);
        uint4 pk;
        pk.x = pack2(o[0], o[1]);
        pk.y = pack2(o[2], o[3]);
        pk.z = pack2(o[4], o[5]);
        pk.w = pack2(o[6], o[7]);
        *(uint4*)(h1 + (size_t)node * 128 + q * 8) = pk;
    }
}

// ---------------- layer-2 aggregation fused with head-mean/relu/proj/softmax ----------------
__global__ __launch_bounds__(256) void agg2_k(const int* __restrict__ offs, const u16* __restrict__ srcs,
                                              const float2* __restrict__ elhs, const float* __restrict__ er,
                                              const signed char* __restrict__ hq,
                                              const float* __restrict__ bias,
                                              const float* __restrict__ Wout, const float* __restrict__ bout,
                                              float2* __restrict__ out) {
    int node = blockIdx.x * 4 + (threadIdx.x >> 6);
    int lane = threadIdx.x & 63;
    if (node >= N_NODES) return;
    float acc[8], den;
    agg_core(node, lane, offs, srcs, elhs, er, hq, acc, den);
    int q = lane & 15;
    float inv = 1.0f / fmaxf(den, 1e-30f);
    float o[8];
#pragma unroll
    for (int i = 0; i < 8; i++) o[i] = acc[i] * inv + bias[q * 8 + i];
    // mean over heads (head = lane bits 2,3), then relu
#pragma unroll
    for (int i = 0; i < 8; i++) {
        o[i] += __shfl_xor(o[i], 4);
        o[i] += __shfl_xor(o[i], 8);
        o[i] = fmaxf(0.25f * o[i], 0.f);
    }
    int d0 = (q & 3) * 8;
    float l0 = 0.f, l1 = 0.f;
#pragma unroll
    for (int i = 0; i < 8; i++) {
        l0 += o[i] * Wout[(d0 + i) * 2];
        l1 += o[i] * Wout[(d0 + i) * 2 + 1];
    }
    l0 += __shfl_xor(l0, 1); l0 += __shfl_xor(l0, 2);
    l1 += __shfl_xor(l1, 1); l1 += __shfl_xor(l1, 2);
    if (lane == 0) {
        l0 += bout[0];
        l1 += bout[1];
        float mx = fmaxf(l0, l1);
        float e0 = __expf(l0 - mx), e1 = __expf(l1 - mx);
        float invs = 1.f / (e0 + e1);
        out[node] = make_float2(e0 * invs, e1 * invs);
    }
}

extern "C" void kernel_launch(void* const* d_in, const int* in_sizes, int n_in,
                              void* d_out, int out_size, void* d_ws, size_t ws_size,
                              hipStream_t stream) {
    const float* in_feat = (const float*)d_in[0];
    const float* W1   = (const float*)d_in[1];
    const float* al1  = (const float*)d_in[2];
    const float* ar1  = (const float*)d_in[3];
    const float* b1   = (const float*)d_in[4];
    const float* W2   = (const float*)d_in[5];
    const float* al2  = (const float*)d_in[6];
    const float* ar2  = (const float*)d_in[7];
    const float* b2   = (const float*)d_in[8];
    const float* Wout = (const float*)d_in[9];
    const float* bout = (const float*)d_in[10];
    const int*   src  = (const int*)d_in[11];
    const int*   dst  = (const int*)d_in[12];
    float* out = (float*)d_out;

    char* ws = (char*)d_ws;
    size_t off = 0;
    auto carve = [&](size_t bytes) {
        char* p = ws + off;
        off = (off + bytes + 255) & ~(size_t)255;
        return p;
    };
    signed char* hq  = (signed char*)carve((size_t)N_NODES * 128);   // int8 features
    float2* elhs     = (float2*)carve((size_t)N_NODES * 4 * 8);      // {el, scale} per (node, head)
    u16*   h1        = (u16*)carve((size_t)N_NODES * 128 * 2);       // layer-1 output (bf16)
    float* er        = (float*)carve((size_t)N_NODES * 4 * 4);
    u16*   srcs      = (u16*)carve((size_t)N_EDGES * 2);
    u32*   bucketed  = (u32*)carve((size_t)N_EDGES * 4);
    u32*   bcnt      = (u32*)carve((size_t)NBUCK * NHB * 4);         // transposed [bucket][blk]
    u32*   wbase     = (u32*)carve((size_t)NBUCK * NHB * 4);
    u32*   btot      = (u32*)carve((size_t)NBUCK * 4);
    int*   offs      = (int*)carve((size_t)(N_NODES + 1) * 4);
    u16*   Wp1       = (u16*)carve((size_t)16384 * 2);
    u16*   Wp2       = (u16*)carve((size_t)16384 * 2);
    (void)ws_size; (void)in_sizes; (void)n_in; (void)out_size;

    const int GB = (N_NODES + 63) / 64;          // 782
    const int AB = (N_NODES + 3) / 4;            // 12500

    // fused cooperative CSR build + weight pre-pack (1 dispatch, 4 grid barriers)
    void* cargs[] = {
        (void*)&src, (void*)&dst, (void*)&W1, (void*)&W2, (void*)&Wp1, (void*)&Wp2,
        (void*)&bcnt, (void*)&wbase, (void*)&btot, (void*)&bucketed, (void*)&offs, (void*)&srcs
    };
    hipLaunchCooperativeKernel((void*)csr_coop_k, dim3(NBUCK), dim3(1024), cargs, 0, stream);

    // layer 1
    gemm_mfma<0><<<GB, 256, 0, stream>>>(in_feat, Wp1, al1, ar1, hq, elhs, er, N_NODES);
    agg1_k<<<AB, 256, 0, stream>>>(offs, srcs, elhs, er, hq, b1, h1);

    // layer 2
    gemm_mfma<1><<<GB, 256, 0, stream>>>(h1, Wp2, al2, ar2, hq, elhs, er, N_NODES);
    agg2_k<<<AB, 256, 0, stream>>>(offs, srcs, elhs, er, hq, b2, Wout, bout, (float2*)out);
}

// Round 14
// 212.890 us; speedup vs baseline: 1.4242x; 1.4242x over previous
//
#include <hip/hip_runtime.h>
#include <cmath>

#define N_NODES 50000
#define N_EDGES 800000
#define NBUCK 196          // buckets of 256 nodes: bucket = dst >> 8
#define NHB 196            // histogram blocks, 4096 edges each
#define EPB 4096
// IN_DIM = HEADS*HID = 128, HEADS=4, HID=32

typedef unsigned short u16;
typedef unsigned int u32;
typedef __attribute__((ext_vector_type(8))) short bf16x8;
typedef __attribute__((ext_vector_type(4))) float f32x4;

static __device__ __forceinline__ float lrelu(float x) { return x > 0.f ? x : 0.2f * x; }
static __device__ __forceinline__ float bf2f(u16 u) { return __uint_as_float(((u32)u) << 16); }
static __device__ __forceinline__ u16 f2bf(float f) {
    u32 b = __float_as_uint(f);
    return (u16)((b + 0x7FFFu + ((b >> 16) & 1u)) >> 16);  // RNE
}
static __device__ __forceinline__ u32 pack2(float a, float b) {
    return (u32)f2bf(a) | ((u32)f2bf(b) << 16);
}
// sign-extended byte k of u -> float
static __device__ __forceinline__ float sx(u32 u, int k) {
    return (float)((int)(u << ((3 - k) * 8)) >> 24);
}

// ---------------- CSR build stage 1 + weight pre-pack (fused dispatch) ----------------
// blocks [0, NHB): per-block histogram, transposed store bcnt[bucket][blk]
// blocks [NHB, NHB+32): pack W1/W2 (fp32 row-major) into bf16 B-fragment order
__global__ __launch_bounds__(1024) void bhist_pack_k(const int* __restrict__ dst, u32* __restrict__ bcnt,
                                                     const float* __restrict__ W1, const float* __restrict__ W2,
                                                     u16* __restrict__ Wp1, u16* __restrict__ Wp2) {
    int tid = threadIdx.x;
    if (blockIdx.x < NHB) {
        __shared__ u32 hist[NBUCK];
        for (int i = tid; i < NBUCK; i += 1024) hist[i] = 0;
        __syncthreads();
        int base = blockIdx.x * EPB;
#pragma unroll
        for (int k = 0; k < 4; ++k) {
            int e = base + k * 1024 + tid;
            if (e < N_EDGES) atomicAdd(&hist[dst[e] >> 8], 1u);
        }
        __syncthreads();
        for (int i = tid; i < NBUCK; i += 1024) bcnt[(size_t)i * NHB + blockIdx.x] = hist[i];
    } else {
        int gi = (blockIdx.x - NHB) * 1024 + tid;   // 0..32767
        const float* W = (gi < 16384) ? W1 : W2;
        u16* Wp = (gi < 16384) ? Wp1 : Wp2;
        int i = gi & 16383;
        int j = i & 7, lane = (i >> 3) & 63, ks = (i >> 9) & 3, nt = i >> 11;
        int k = ks * 32 + (lane >> 4) * 8 + j;
        int ncol = nt * 16 + (lane & 15);
        Wp[i] = f2bf(W[k * 128 + ncol]);
    }
}

// 2a) per-bucket exclusive scan over hist blocks (196 parallel blocks)
__global__ __launch_bounds__(256) void scant_k(const u32* __restrict__ bcnt, u32* __restrict__ wbase,
                                               u32* __restrict__ btot) {
    __shared__ u32 s[256];
    int i = blockIdx.x, t = threadIdx.x;
    u32 v = (t < NHB) ? bcnt[(size_t)i * NHB + t] : 0;
    s[t] = v;
    __syncthreads();
    for (int o = 1; o < 256; o <<= 1) {
        u32 x = (t >= o) ? s[t - o] : 0;
        __syncthreads();
        s[t] += x;
        __syncthreads();
    }
    if (t < NHB) wbase[(size_t)i * NHB + t] = s[t] - v;
    if (t == 255) btot[i] = s[255];
}

// 2b) bucket starts
__global__ __launch_bounds__(256) void scanb2_k(const u32* __restrict__ btot, int* __restrict__ bstart) {
    __shared__ u32 s[256];
    int t = threadIdx.x;
    u32 v = (t < NBUCK) ? btot[t] : 0;
    s[t] = v;
    __syncthreads();
    for (int o = 1; o < 256; o <<= 1) {
        u32 x = (t >= o) ? s[t - o] : 0;
        __syncthreads();
        s[t] += x;
        __syncthreads();
    }
    if (t < NBUCK) bstart[t] = (int)(s[t] - v);
    if (t == NBUCK - 1) bstart[NBUCK] = (int)s[t];
}

// 3) scatter edges into bucket-contiguous array; payload = src(16b) | dst_low8(<<16)
__global__ __launch_bounds__(1024) void bscatter_k(const int* __restrict__ src, const int* __restrict__ dst,
                                                   const u32* __restrict__ wbase, const int* __restrict__ bstart,
                                                   u32* __restrict__ bucketed) {
    __shared__ u32 pos[NBUCK];
    int tid = threadIdx.x;
    for (int i = tid; i < NBUCK; i += 1024)
        pos[i] = (u32)bstart[i] + wbase[(size_t)i * NHB + blockIdx.x];
    __syncthreads();
    int base = blockIdx.x * EPB;
#pragma unroll
    for (int k = 0; k < 4; ++k) {
        int e = base + k * 1024 + tid;
        if (e < N_EDGES) {
            int d = dst[e];
            int b = d >> 8;
            u32 p = atomicAdd(&pos[b], 1u);
            bucketed[p] = (u32)src[e] | ((u32)(d & 255) << 16);
        }
    }
}

// 4) per-bucket fine CSR: node offs + u16 srcs
__global__ __launch_bounds__(256) void bcsr_k(const u32* __restrict__ bucketed, const int* __restrict__ bstart,
                                              int* __restrict__ offs, u16* __restrict__ srcs) {
    __shared__ u32 cnt[256];
    __shared__ int s[256];
    __shared__ u32 fp[256];
    int b = blockIdx.x;
    int tid = threadIdx.x;
    int ebeg = bstart[b], eend = bstart[b + 1];
    int ne = eend - ebeg;
    cnt[tid] = 0;
    __syncthreads();
    for (int i = tid; i < ne; i += 256)
        atomicAdd(&cnt[bucketed[ebeg + i] >> 16], 1u);
    __syncthreads();
    s[tid] = (int)cnt[tid];
    __syncthreads();
    for (int o = 1; o < 256; o <<= 1) {
        int v = (tid >= o) ? s[tid - o] : 0;
        __syncthreads();
        s[tid] += v;
        __syncthreads();
    }
    int excl = s[tid] - (int)cnt[tid];
    int node = b * 256 + tid;
    if (node < N_NODES) offs[node] = ebeg + excl;
    if (b == NBUCK - 1 && tid == 0) offs[N_NODES] = N_EDGES;
    fp[tid] = (u32)excl;
    __syncthreads();
    for (int i = tid; i < ne; i += 256) {
        u32 u = bucketed[ebeg + i];
        u32 p = atomicAdd(&fp[u >> 16], 1u);
        srcs[ebeg + p] = (u16)(u & 0xFFFFu);
    }
}

// ---------------- MFMA GEMM -> int8 hf + fused {el,scale} float2 + er ----------------
// hq: int8 [N][128]; elhs: float2 [N][4] = {el, absmax/127}; er: fp32 [N][4]. wave = head.
template <int BF16IN>
__global__ __launch_bounds__(256) void gemm_mfma(
    const void* __restrict__ Xv, const u16* __restrict__ Wp,
    const float* __restrict__ al, const float* __restrict__ ar,
    signed char* __restrict__ hq, float2* __restrict__ elhs, float* __restrict__ er, int n)
{
    __shared__ u16 xs[64][136];   // +8 pad: 2-way LDS bank aliasing (free)
    int row0 = blockIdx.x * 64;
    int tid = threadIdx.x;
    if (BF16IN) {
        const uint4* Xb = (const uint4*)Xv;
        for (int i = tid; i < 1024; i += 256) {
            int r = i >> 4, c = i & 15;
            uint4 v = make_uint4(0u, 0u, 0u, 0u);
            if (row0 + r < n) v = Xb[(size_t)(row0 + r) * 16 + c];
            ((uint4*)&xs[r][0])[c] = v;
        }
    } else {
        const float4* X4 = (const float4*)Xv;
        for (int i = tid; i < 2048; i += 256) {
            int r = i >> 5, c = i & 31;
            float4 v = make_float4(0.f, 0.f, 0.f, 0.f);
            if (row0 + r < n) v = X4[(size_t)(row0 + r) * 32 + c];
            ((uint2*)&xs[r][0])[c] = make_uint2(pack2(v.x, v.y), pack2(v.z, v.w));
        }
    }
    __syncthreads();

    int wave = tid >> 6, lane = tid & 63;
    int quad = lane >> 4, l15 = lane & 15;

    bf16x8 bfrag[2][4];
#pragma unroll
    for (int ct = 0; ct < 2; ++ct) {
        int nt = wave * 2 + ct;
#pragma unroll
        for (int ks = 0; ks < 4; ++ks)
            bfrag[ct][ks] = *(const bf16x8*)(Wp + ((((nt * 4 + ks) * 64) + lane) << 3));
    }

    f32x4 acc[4][2];
#pragma unroll
    for (int rt = 0; rt < 4; ++rt)
#pragma unroll
        for (int ct = 0; ct < 2; ++ct)
            acc[rt][ct] = (f32x4){0.f, 0.f, 0.f, 0.f};

#pragma unroll
    for (int ks = 0; ks < 4; ++ks) {
#pragma unroll
        for (int rt = 0; rt < 4; ++rt) {
            bf16x8 a = *(const bf16x8*)&xs[rt * 16 + l15][ks * 32 + quad * 8];
            acc[rt][0] = __builtin_amdgcn_mfma_f32_16x16x32_bf16(a, bfrag[0][ks], acc[rt][0], 0, 0, 0);
            acc[rt][1] = __builtin_amdgcn_mfma_f32_16x16x32_bf16(a, bfrag[1][ks], acc[rt][1], 0, 0, 0);
        }
    }

    float alv0 = al[wave * 32 + l15], alv1 = al[wave * 32 + 16 + l15];
    float arv0 = ar[wave * 32 + l15], arv1 = ar[wave * 32 + 16 + l15];
#pragma unroll
    for (int rt = 0; rt < 4; ++rt) {
#pragma unroll
        for (int r = 0; r < 4; ++r) {
            int row = row0 + rt * 16 + quad * 4 + r;
            float c0 = acc[rt][0][r], c1 = acc[rt][1][r];
            // per-(row, head) absmax over the wave's 32 cols (reduce over l15 lanes)
            float m = fmaxf(fabsf(c0), fabsf(c1));
            m = fmaxf(m, __shfl_xor(m, 1));
            m = fmaxf(m, __shfl_xor(m, 2));
            m = fmaxf(m, __shfl_xor(m, 4));
            m = fmaxf(m, __shfl_xor(m, 8));
            m = fmaxf(m, 1e-20f);
            float qsc = 127.0f / m;
            if (row < n) {
                hq[(size_t)row * 128 + wave * 32 + l15] = (signed char)(int)rintf(c0 * qsc);
                hq[(size_t)row * 128 + wave * 32 + 16 + l15] = (signed char)(int)rintf(c1 * qsc);
            }
            float pel = c0 * alv0 + c1 * alv1;
            float per = c0 * arv0 + c1 * arv1;
            pel += __shfl_xor(pel, 1); pel += __shfl_xor(pel, 2);
            pel += __shfl_xor(pel, 4); pel += __shfl_xor(pel, 8);
            per += __shfl_xor(per, 1); per += __shfl_xor(per, 2);
            per += __shfl_xor(per, 4); per += __shfl_xor(per, 8);
            if (l15 == 0 && row < n) {
                elhs[row * 4 + wave] = make_float2(pel, m * (1.0f / 127.0f));
                er[row * 4 + wave] = per;
            }
        }
    }
}

// ---------------- agg core: quarter-wave per edge, lane owns 8 int8 features (uint2) ---------
// Two gather streams per edge: elhs (8B) + hq (8B). srcs preloaded via one coalesced load+shfl.
static __device__ __forceinline__ void agg_core(
    int node, int lane, const int* __restrict__ offs, const u16* __restrict__ srcs,
    const float2* __restrict__ elhs, const float* __restrict__ er,
    const signed char* __restrict__ hq,
    float acc[8], float& den)
{
    int qw = lane >> 4;
    int q = lane & 15;
    int h = q >> 2;
    float erh = er[node * 4 + h];
    int beg = offs[node], end = offs[node + 1];
    int deg = end - beg;
    den = 0.f;
#pragma unroll
    for (int i = 0; i < 8; i++) acc[i] = 0.f;

    if (deg <= 64) {
        int psrc = (lane < deg) ? (int)srcs[beg + lane] : 0;
        int base = beg;
        for (; base + 16 <= end; base += 16) {
            int j = base - beg + qw;
            int ss[4];
            ss[0] = __shfl(psrc, j);
            ss[1] = __shfl(psrc, j + 4);
            ss[2] = __shfl(psrc, j + 8);
            ss[3] = __shfl(psrc, j + 12);
            float2 eh[4];
            uint2 uv[4];
#pragma unroll
            for (int k = 0; k < 4; ++k) {
                eh[k] = elhs[ss[k] * 4 + h];
                uv[k] = *(const uint2*)(hq + (size_t)ss[k] * 128 + q * 8);
            }
#pragma unroll
            for (int k = 0; k < 4; ++k) {
                float w = __expf(lrelu(eh[k].x + erh));
                float ws = w * eh[k].y;
                den += w;
                acc[0] += ws * sx(uv[k].x, 0);
                acc[1] += ws * sx(uv[k].x, 1);
                acc[2] += ws * sx(uv[k].x, 2);
                acc[3] += ws * sx(uv[k].x, 3);
                acc[4] += ws * sx(uv[k].y, 0);
                acc[5] += ws * sx(uv[k].y, 1);
                acc[6] += ws * sx(uv[k].y, 2);
                acc[7] += ws * sx(uv[k].y, 3);
            }
        }
        for (; base + 8 <= end; base += 8) {
            int j = base - beg + qw;
            int s0 = __shfl(psrc, j);
            int s1 = __shfl(psrc, j + 4);
            float2 e0 = elhs[s0 * 4 + h], e1 = elhs[s1 * 4 + h];
            uint2 u0 = *(const uint2*)(hq + (size_t)s0 * 128 + q * 8);
            uint2 u1 = *(const uint2*)(hq + (size_t)s1 * 128 + q * 8);
            float w0 = __expf(lrelu(e0.x + erh));
            float w1 = __expf(lrelu(e1.x + erh));
            float ws0 = w0 * e0.y, ws1 = w1 * e1.y;
            den += w0 + w1;
            acc[0] += ws0 * sx(u0.x, 0) + ws1 * sx(u1.x, 0);
            acc[1] += ws0 * sx(u0.x, 1) + ws1 * sx(u1.x, 1);
            acc[2] += ws0 * sx(u0.x, 2) + ws1 * sx(u1.x, 2);
            acc[3] += ws0 * sx(u0.x, 3) + ws1 * sx(u1.x, 3);
            acc[4] += ws0 * sx(u0.y, 0) + ws1 * sx(u1.y, 0);
            acc[5] += ws0 * sx(u0.y, 1) + ws1 * sx(u1.y, 1);
            acc[6] += ws0 * sx(u0.y, 2) + ws1 * sx(u1.y, 2);
            acc[7] += ws0 * sx(u0.y, 3) + ws1 * sx(u1.y, 3);
        }
        for (; base < end; base += 4) {
            int e = base + qw;
            bool valid = e < end;
            int j = valid ? (e - beg) : 0;
            int s = __shfl(psrc, j);
            float2 eh = elhs[s * 4 + h];
            float w = valid ? __expf(lrelu(eh.x + erh)) : 0.f;
            float ws = w * eh.y;
            uint2 u = *(const uint2*)(hq + (size_t)s * 128 + q * 8);
            den += w;
            acc[0] += ws * sx(u.x, 0);
            acc[1] += ws * sx(u.x, 1);
            acc[2] += ws * sx(u.x, 2);
            acc[3] += ws * sx(u.x, 3);
            acc[4] += ws * sx(u.y, 0);
            acc[5] += ws * sx(u.y, 1);
            acc[6] += ws * sx(u.y, 2);
            acc[7] += ws * sx(u.y, 3);
        }
    } else {
        for (int base = beg; base < end; base += 4) {
            int e = base + qw;
            bool valid = e < end;
            int ec = valid ? e : end - 1;
            int s = srcs[ec];
            float2 eh = elhs[s * 4 + h];
            float w = valid ? __expf(lrelu(eh.x + erh)) : 0.f;
            float ws = w * eh.y;
            uint2 u = *(const uint2*)(hq + (size_t)s * 128 + q * 8);
            den += w;
            acc[0] += ws * sx(u.x, 0);
            acc[1] += ws * sx(u.x, 1);
            acc[2] += ws * sx(u.x, 2);
            acc[3] += ws * sx(u.x, 3);
            acc[4] += ws * sx(u.y, 0);
            acc[5] += ws * sx(u.y, 1);
            acc[6] += ws * sx(u.y, 2);
            acc[7] += ws * sx(u.y, 3);
        }
    }
#pragma unroll
    for (int i = 0; i < 8; i++) {
        acc[i] += __shfl_xor(acc[i], 16);
        acc[i] += __shfl_xor(acc[i], 32);
    }
    den += __shfl_xor(den, 16);
    den += __shfl_xor(den, 32);
}

// ---------------- layer-1 aggregation (relu, bf16 out node-major) ----------------
__global__ __launch_bounds__(256) void agg1_k(const int* __restrict__ offs, const u16* __restrict__ srcs,
                                              const float2* __restrict__ elhs, const float* __restrict__ er,
                                              const signed char* __restrict__ hq,
                                              const float* __restrict__ bias, u16* __restrict__ h1) {
    int node = blockIdx.x * 4 + (threadIdx.x >> 6);
    int lane = threadIdx.x & 63;
    if (node >= N_NODES) return;
    float acc[8], den;
    agg_core(node, lane, offs, srcs, elhs, er, hq, acc, den);
    int qw = lane >> 4, q = lane & 15;
    if (qw == 0) {
        float inv = 1.0f / fmaxf(den, 1e-30f);
        float o[8];
#pragma unroll
        for (int i = 0; i < 8; i++)
            o[i] = fmaxf(acc[i] * inv + bias[q * 8 + i], 0.f);
        uint4 pk;
        pk.x = pack2(o[0], o[1]);
        pk.y = pack2(o[2], o[3]);
        pk.z = pack2(o[4], o[5]);
        pk.w = pack2(o[6], o[7]);
        *(uint4*)(h1 + (size_t)node * 128 + q * 8) = pk;
    }
}

// ---------------- layer-2 aggregation fused with head-mean/relu/proj/softmax ----------------
__global__ __launch_bounds__(256) void agg2_k(const int* __restrict__ offs, const u16* __restrict__ srcs,
                                              const float2* __restrict__ elhs, const float* __restrict__ er,
                                              const signed char* __restrict__ hq,
                                              const float* __restrict__ bias,
                                              const float* __restrict__ Wout, const float* __restrict__ bout,
                                              float2* __restrict__ out) {
    int node = blockIdx.x * 4 + (threadIdx.x >> 6);
    int lane = threadIdx.x & 63;
    if (node >= N_NODES) return;
    float acc[8], den;
    agg_core(node, lane, offs, srcs, elhs, er, hq, acc, den);
    int q = lane & 15;
    float inv = 1.0f / fmaxf(den, 1e-30f);
    float o[8];
#pragma unroll
    for (int i = 0; i < 8; i++) o[i] = acc[i] * inv + bias[q * 8 + i];
    // mean over heads (head = lane bits 2,3), then relu
#pragma unroll
    for (int i = 0; i < 8; i++) {
        o[i] += __shfl_xor(o[i], 4);
        o[i] += __shfl_xor(o[i], 8);
        o[i] = fmaxf(0.25f * o[i], 0.f);
    }
    int d0 = (q & 3) * 8;
    float l0 = 0.f, l1 = 0.f;
#pragma unroll
    for (int i = 0; i < 8; i++) {
        l0 += o[i] * Wout[(d0 + i) * 2];
        l1 += o[i] * Wout[(d0 + i) * 2 + 1];
    }
    l0 += __shfl_xor(l0, 1); l0 += __shfl_xor(l0, 2);
    l1 += __shfl_xor(l1, 1); l1 += __shfl_xor(l1, 2);
    if (lane == 0) {
        l0 += bout[0];
        l1 += bout[1];
        float mx = fmaxf(l0, l1);
        float e0 = __expf(l0 - mx), e1 = __expf(l1 - mx);
        float invs = 1.f / (e0 + e1);
        out[node] = make_float2(e0 * invs, e1 * invs);
    }
}

extern "C" void kernel_launch(void* const* d_in, const int* in_sizes, int n_in,
                              void* d_out, int out_size, void* d_ws, size_t ws_size,
                              hipStream_t stream) {
    const float* in_feat = (const float*)d_in[0];
    const float* W1   = (const float*)d_in[1];
    const float* al1  = (const float*)d_in[2];
    const float* ar1  = (const float*)d_in[3];
    const float* b1   = (const float*)d_in[4];
    const float* W2   = (const float*)d_in[5];
    const float* al2  = (const float*)d_in[6];
    const float* ar2  = (const float*)d_in[7];
    const float* b2   = (const float*)d_in[8];
    const float* Wout = (const float*)d_in[9];
    const float* bout = (const float*)d_in[10];
    const int*   src  = (const int*)d_in[11];
    const int*   dst  = (const int*)d_in[12];
    float* out = (float*)d_out;

    char* ws = (char*)d_ws;
    size_t off = 0;
    auto carve = [&](size_t bytes) {
        char* p = ws + off;
        off = (off + bytes + 255) & ~(size_t)255;
        return p;
    };
    signed char* hq  = (signed char*)carve((size_t)N_NODES * 128);   // int8 features
    float2* elhs     = (float2*)carve((size_t)N_NODES * 4 * 8);      // {el, scale} per (node, head)
    u16*   h1        = (u16*)carve((size_t)N_NODES * 128 * 2);       // layer-1 output (bf16)
    float* er        = (float*)carve((size_t)N_NODES * 4 * 4);
    u16*   srcs      = (u16*)carve((size_t)N_EDGES * 2);
    u32*   bucketed  = (u32*)carve((size_t)N_EDGES * 4);
    u32*   bcnt      = (u32*)carve((size_t)NBUCK * NHB * 4);         // transposed [bucket][blk]
    u32*   wbase     = (u32*)carve((size_t)NBUCK * NHB * 4);
    u32*   btot      = (u32*)carve((size_t)NBUCK * 4);
    int*   bstart    = (int*)carve((size_t)(NBUCK + 1) * 4);
    int*   offs      = (int*)carve((size_t)(N_NODES + 1) * 4);
    u16*   Wp1       = (u16*)carve((size_t)16384 * 2);
    u16*   Wp2       = (u16*)carve((size_t)16384 * 2);
    (void)ws_size; (void)in_sizes; (void)n_in; (void)out_size;

    const int GB = (N_NODES + 63) / 64;          // 782
    const int AB = (N_NODES + 3) / 4;            // 12500

    // bucketed CSR build (+ fused weight pre-pack)
    bhist_pack_k<<<NHB + 32, 1024, 0, stream>>>(dst, bcnt, W1, W2, Wp1, Wp2);
    scant_k<<<NBUCK, 256, 0, stream>>>(bcnt, wbase, btot);
    scanb2_k<<<1, 256, 0, stream>>>(btot, bstart);
    bscatter_k<<<NHB, 1024, 0, stream>>>(src, dst, wbase, bstart, bucketed);
    bcsr_k<<<NBUCK, 256, 0, stream>>>(bucketed, bstart, offs, srcs);

    // layer 1
    gemm_mfma<0><<<GB, 256, 0, stream>>>(in_feat, Wp1, al1, ar1, hq, elhs, er, N_NODES);
    agg1_k<<<AB, 256, 0, stream>>>(offs, srcs, elhs, er, hq, b1, h1);

    // layer 2
    gemm_mfma<1><<<GB, 256, 0, stream>>>(h1, Wp2, al2, ar2, hq, elhs, er, N_NODES);
    agg2_k<<<AB, 256, 0, stream>>>(offs, srcs, elhs, er, hq, b2, Wout, bout, (float2*)out);
}